// Round 1
// baseline (1058.529 us; speedup 1.0000x reference)
//
#include <hip/hip_runtime.h>
#include <math.h>

// GCN: h1 = relu(GCNConv(x, W1, b1)); h2 = relu(GCNConv(h1, W2, b2)); out = sigmoid(h2 @ Wfc + bfc)
// GCNConv with self-loops + symmetric norm:
//   out[d] = dinv[d] * ( sum_{(s->d) in E} g[s] + g[d] ) + b,   g[i] = (x[i] @ W) * dinv[i]
//   deg[i] = (# edges with dst == i) + 1;  dinv = rsqrt(deg)

#define TPB 256

__global__ void k_init_deg(float* __restrict__ deg, int n) {
    int i = blockIdx.x * blockDim.x + threadIdx.x;
    if (i < n) deg[i] = 1.0f;  // self-loop
}

__global__ void k_count(const int* __restrict__ dst, float* __restrict__ deg, int e) {
    int i = blockIdx.x * blockDim.x + threadIdx.x;
    if (i < e) atomicAdd(&deg[dst[i]], 1.0f);
}

__global__ void k_dinv(float* __restrict__ deg, int n) {
    int i = blockIdx.x * blockDim.x + threadIdx.x;
    if (i < n) deg[i] = rsqrtf(deg[i]);  // deg >= 1 always
}

// g1[i] = (x[i] @ W1) * dinv[i]; agg1 initialized with g1 (self-loop term)
__global__ void k_layer1(const float* __restrict__ x, const float* __restrict__ W1,
                         const float* __restrict__ dinv,
                         float* __restrict__ g1, float* __restrict__ agg1, int n) {
    __shared__ float w[96];  // 6 x 16
    if (threadIdx.x < 96) w[threadIdx.x] = W1[threadIdx.x];
    __syncthreads();
    int i = blockIdx.x * blockDim.x + threadIdx.x;
    if (i >= n) return;
    float xv[6];
#pragma unroll
    for (int k = 0; k < 6; k++) xv[k] = x[i * 6 + k];
    float di = dinv[i];
#pragma unroll
    for (int f = 0; f < 16; f++) {
        float h = 0.0f;
#pragma unroll
        for (int k = 0; k < 6; k++) h += xv[k] * w[k * 16 + f];
        float g = h * di;
        g1[i * 16 + f] = g;
        agg1[i * 16 + f] = g;
    }
}

// one thread per (edge, feature); F = 16
__global__ void k_scatter16(const int* __restrict__ src, const int* __restrict__ dst,
                            const float* __restrict__ g, float* __restrict__ agg, int e) {
    int t = blockIdx.x * blockDim.x + threadIdx.x;
    if (t >= e * 16) return;
    int ed = t >> 4, f = t & 15;
    int s = src[ed], d = dst[ed];
    atomicAdd(&agg[d * 16 + f], g[s * 16 + f]);
}

// h = relu(dinv*agg1 + b1); g2[i] = (h @ W2) * dinv[i]; agg2 init with g2
__global__ void k_layer2(const float* __restrict__ agg1, const float* __restrict__ dinv,
                         const float* __restrict__ W2, const float* __restrict__ b1,
                         float* __restrict__ g2, float* __restrict__ agg2, int n) {
    __shared__ float w[128];  // 16 x 8
    __shared__ float bb[16];
    if (threadIdx.x < 128) w[threadIdx.x] = W2[threadIdx.x];
    if (threadIdx.x < 16) bb[threadIdx.x] = b1[threadIdx.x];
    __syncthreads();
    int i = blockIdx.x * blockDim.x + threadIdx.x;
    if (i >= n) return;
    float di = dinv[i];
    float t[16];
#pragma unroll
    for (int f = 0; f < 16; f++) t[f] = fmaxf(di * agg1[i * 16 + f] + bb[f], 0.0f);
#pragma unroll
    for (int f2 = 0; f2 < 8; f2++) {
        float h = 0.0f;
#pragma unroll
        for (int f = 0; f < 16; f++) h += t[f] * w[f * 8 + f2];
        float g = h * di;
        g2[i * 8 + f2] = g;
        agg2[i * 8 + f2] = g;
    }
}

// one thread per (edge, feature); F = 8
__global__ void k_scatter8(const int* __restrict__ src, const int* __restrict__ dst,
                           const float* __restrict__ g, float* __restrict__ agg, int e) {
    int t = blockIdx.x * blockDim.x + threadIdx.x;
    if (t >= e * 8) return;
    int ed = t >> 3, f = t & 7;
    int s = src[ed], d = dst[ed];
    atomicAdd(&agg[d * 8 + f], g[s * 8 + f]);
}

// h = relu(dinv*agg2 + b2); out = sigmoid(h @ Wfc + bfc)
__global__ void k_final(const float* __restrict__ agg2, const float* __restrict__ dinv,
                        const float* __restrict__ b2, const float* __restrict__ Wfc,
                        const float* __restrict__ bfc, float* __restrict__ out, int n) {
    __shared__ float w[8];
    __shared__ float bb[8];
    __shared__ float bf;
    if (threadIdx.x < 8) { w[threadIdx.x] = Wfc[threadIdx.x]; bb[threadIdx.x] = b2[threadIdx.x]; }
    if (threadIdx.x == 0) bf = bfc[0];
    __syncthreads();
    int i = blockIdx.x * blockDim.x + threadIdx.x;
    if (i >= n) return;
    float di = dinv[i];
    float o = bf;
#pragma unroll
    for (int f = 0; f < 8; f++) {
        float h = fmaxf(di * agg2[i * 8 + f] + bb[f], 0.0f);
        o += h * w[f];
    }
    out[i] = 1.0f / (1.0f + expf(-o));
}

extern "C" void kernel_launch(void* const* d_in, const int* in_sizes, int n_in,
                              void* d_out, int out_size, void* d_ws, size_t ws_size,
                              hipStream_t stream) {
    const float* x   = (const float*)d_in[0];
    const int*   ei  = (const int*)d_in[1];
    const float* W1  = (const float*)d_in[2];
    const float* b1  = (const float*)d_in[3];
    const float* W2  = (const float*)d_in[4];
    const float* b2  = (const float*)d_in[5];
    const float* Wfc = (const float*)d_in[6];
    const float* bfc = (const float*)d_in[7];
    float* out = (float*)d_out;

    const int n = in_sizes[0] / 6;   // 200000
    const int e = in_sizes[1] / 2;   // 6400000
    const int* src = ei;
    const int* dst = ei + e;

    float* ws   = (float*)d_ws;
    float* deg  = ws;              // n  (becomes dinv in-place)
    float* g1   = deg + n;         // 16n
    float* agg1 = g1 + 16 * (size_t)n;   // 16n
    float* g2   = agg1 + 16 * (size_t)n; // 8n
    float* agg2 = g2 + 8 * (size_t)n;    // 8n

    int gn = (n + TPB - 1) / TPB;
    int ge = (e + TPB - 1) / TPB;

    k_init_deg<<<gn, TPB, 0, stream>>>(deg, n);
    k_count<<<ge, TPB, 0, stream>>>(dst, deg, e);
    k_dinv<<<gn, TPB, 0, stream>>>(deg, n);

    k_layer1<<<gn, TPB, 0, stream>>>(x, W1, deg, g1, agg1, n);
    {
        long long tot = (long long)e * 16;
        int blocks = (int)((tot + TPB - 1) / TPB);
        k_scatter16<<<blocks, TPB, 0, stream>>>(src, dst, g1, agg1, e);
    }
    k_layer2<<<gn, TPB, 0, stream>>>(agg1, deg, W2, b1, g2, agg2, n);
    {
        long long tot = (long long)e * 8;
        int blocks = (int)((tot + TPB - 1) / TPB);
        k_scatter8<<<blocks, TPB, 0, stream>>>(src, dst, g2, agg2, e);
    }
    k_final<<<gn, TPB, 0, stream>>>(agg2, deg, b2, Wfc, bfc, out, n);
}